// Round 1
// baseline (665.860 us; speedup 1.0000x reference)
//
#include <hip/hip_runtime.h>
#include <hip/hip_bf16.h>
#include <cstdint>
#include <cstddef>

// Problem constants (Qwen2: B=2,S=4096,H=3584,NH=28,NKV=4,D=128)
#define SS 4096
#define HH 3584
#define NHQ 28
#define NKVH 4
#define DD 128
#define MM 8192                 // B*S
#define NN 4608                 // (NH+2*NKV)*D
#define KK 3584
#define NKT 112                 // KK/32
#define NBM 64                  // MM/128
#define NBN 36                  // NN/128
#define QOFF 0
#define KOFF 29360128ULL        // B*NH*S*D
#define VOFF 33554432ULL        // KOFF + B*NKV*S*D

typedef __bf16 bf16;
typedef bf16  bf16x8  __attribute__((ext_vector_type(8)));
typedef float floatx4 __attribute__((ext_vector_type(4)));

// ---------------------------------------------------------------- prep A ----
__global__ __launch_bounds__(256) void cvt_a(const float* __restrict__ src,
                                             bf16* __restrict__ dst, int n8) {
    int i = blockIdx.x * 256 + threadIdx.x;
    if (i >= n8) return;
    const float4* s = (const float4*)src;
    float4 a = s[2 * i];
    float4 b = s[2 * i + 1];
    bf16x8 o;
    o[0] = (bf16)a.x; o[1] = (bf16)a.y; o[2] = (bf16)a.z; o[3] = (bf16)a.w;
    o[4] = (bf16)b.x; o[5] = (bf16)b.y; o[6] = (bf16)b.z; o[7] = (bf16)b.w;
    *(bf16x8*)(dst + (size_t)i * 8) = o;
}

// ------------------------------------------------- prep B: transpose+cvt ----
// Bt[row_off + n][k] = (bf16) W[k][n],  W is KK x ncols row-major
__global__ __launch_bounds__(256) void tr_cvt(const float* __restrict__ W,
                                              bf16* __restrict__ Bt,
                                              int ncols, int row_off) {
    __shared__ float tile[32][33];
    int n0 = blockIdx.x * 32;
    int k0 = blockIdx.y * 32;
    int lx = threadIdx.x & 31;
    int ly = threadIdx.x >> 5;          // 0..7
#pragma unroll
    for (int i = 0; i < 32; i += 8)
        tile[ly + i][lx] = W[(size_t)(k0 + ly + i) * ncols + n0 + lx];
    __syncthreads();
#pragma unroll
    for (int i = 0; i < 32; i += 8)
        Bt[(size_t)(row_off + n0 + ly + i) * KK + k0 + lx] = (bf16)tile[lx][ly + i];
}

// ----------------------------------------------------------------- GEMM -----
__device__ __forceinline__ void g2l16(const void* g, void* l) {
    __builtin_amdgcn_global_load_lds(
        (const __attribute__((address_space(1))) void*)g,
        (__attribute__((address_space(3))) void*)l, 16, 0, 0);
}

__global__ __launch_bounds__(256) void qkv_gemm(
    const bf16* __restrict__ A, const bf16* __restrict__ Bt,
    const float* __restrict__ bq, const float* __restrict__ bk,
    const float* __restrict__ bv, const float* __restrict__ cosp,
    const float* __restrict__ sinp, float* __restrict__ out) {

    __shared__ __align__(16) bf16 As[128 * 32];   // (row, k) row-major, 8 KB
    __shared__ __align__(16) bf16 Bs[128 * 32];   // (n,   k) row-major, 8 KB

    const int tid  = threadIdx.x;
    const int lane = tid & 63;
    const int wave = tid >> 6;          // 0..3
    const int wm   = wave >> 1;         // wave m-half
    const int wn   = wave & 1;          // wave n-group
    const int bm   = blockIdx.x / NBN;
    const int bn   = blockIdx.x % NBN;
    const int m0   = bm * 128;
    const int n0   = bn * 128;          // block owns exactly one head (128 cols)

    // ---- staging addresses: tile row = (wave*2+i)*16 + lane/4, k-quarter = lane%4
    const int srow = lane >> 2;
    const int skq  = lane & 3;
    const bf16* ag0 = A  + (size_t)(m0 + wave * 32 + srow) * KK + skq * 8;
    const bf16* ag1 = ag0 + (size_t)16 * KK;
    const bf16* bg0 = Bt + (size_t)(n0 + wave * 32 + srow) * KK + skq * 8;
    const bf16* bg1 = bg0 + (size_t)16 * KK;
    // LDS dst must be wave-uniform base + lane*16 bytes (= lane*8 elements)
    bf16* al0 = As + (wave * 2 + 0) * 512 + lane * 8;
    bf16* al1 = As + (wave * 2 + 1) * 512 + lane * 8;
    bf16* bl0 = Bs + (wave * 2 + 0) * 512 + lane * 8;
    bf16* bl1 = Bs + (wave * 2 + 1) * 512 + lane * 8;

    // ---- fragment read addresses (16x16x32: m/n = lane&15, k = (lane>>4)*8+j)
    const int fr = lane & 15;
    const int fq = lane >> 4;
    const bf16* ar[4];
    const bf16* br[4];
#pragma unroll
    for (int mi = 0; mi < 4; ++mi)
        ar[mi] = As + (wm * 64 + mi * 16 + fr) * 32 + fq * 8;
    // RoPE-friendly n-tile assignment: wave wn owns col bases
    //   ni=0: wn*32+0   ni=1: wn*32+64   ni=2: wn*32+16   ni=3: wn*32+80
    // so (2p, 2p+1) is the (d, d+64) rotate pair in the SAME lane.
#pragma unroll
    for (int ni = 0; ni < 4; ++ni) {
        int ncol = wn * 32 + (ni >> 1) * 16 + (ni & 1) * 64;
        br[ni] = Bs + (ncol + fr) * 32 + fq * 8;
    }

    floatx4 acc[4][4];
#pragma unroll
    for (int mi = 0; mi < 4; ++mi)
#pragma unroll
        for (int ni = 0; ni < 4; ++ni)
            acc[mi][ni] = (floatx4){0.f, 0.f, 0.f, 0.f};

    for (int kt = 0; kt < NKT; ++kt) {
        __syncthreads();                      // previous compute done
        g2l16(ag0, al0); g2l16(ag1, al1);
        g2l16(bg0, bl0); g2l16(bg1, bl1);
        ag0 += 32; ag1 += 32; bg0 += 32; bg1 += 32;
        __syncthreads();                      // drains vmcnt -> LDS tiles ready

        bf16x8 af[4], bfr[4];
#pragma unroll
        for (int mi = 0; mi < 4; ++mi) af[mi] = *(const bf16x8*)ar[mi];
#pragma unroll
        for (int ni = 0; ni < 4; ++ni) bfr[ni] = *(const bf16x8*)br[ni];
#pragma unroll
        for (int mi = 0; mi < 4; ++mi)
#pragma unroll
            for (int ni = 0; ni < 4; ++ni)
                acc[mi][ni] = __builtin_amdgcn_mfma_f32_16x16x32_bf16(
                    af[mi], bfr[ni], acc[mi][ni], 0, 0, 0);
    }

    // ---- epilogue: bias + RoPE (register-local pairs) + permuted store -----
    const float* bias;
    int h, nh;
    size_t obase;
    bool rope;
    if (n0 < 3584)      { bias = bq + n0;          h = n0 >> 7;          obase = QOFF; nh = NHQ;  rope = true;  }
    else if (n0 < 4096) { bias = bk + (n0 - 3584); h = (n0 - 3584) >> 7; obase = KOFF; nh = NKVH; rope = true;  }
    else                { bias = bv + (n0 - 4096); h = (n0 - 4096) >> 7; obase = VOFF; nh = NKVH; rope = false; }

    float blo[2], bhi[2];
#pragma unroll
    for (int p = 0; p < 2; ++p) {
        int d = wn * 32 + p * 16 + fr;     // in [0,64)
        blo[p] = bias[d];
        bhi[p] = bias[d + 64];
    }

#pragma unroll
    for (int mi = 0; mi < 4; ++mi) {
#pragma unroll
        for (int r = 0; r < 4; ++r) {
            int m = m0 + wm * 64 + mi * 16 + fq * 4 + r;   // C/D: row=quad*4+reg
            int b = m >> 12;                                // m / S
            int s = m & 4095;                               // m % S
            size_t orow = obase + ((size_t)(b * nh + h) * SS + s) * DD;
#pragma unroll
            for (int p = 0; p < 2; ++p) {
                int d = wn * 32 + p * 16 + fr;
                float xlo = acc[mi][2 * p][r] + blo[p];
                float xhi = acc[mi][2 * p + 1][r] + bhi[p];
                float ylo, yhi;
                if (rope) {
                    float c  = cosp[(size_t)m * DD + d];
                    float sn = sinp[(size_t)m * DD + d];
                    ylo = xlo * c - xhi * sn;      // d < 64:  x*cos - x_hi*sin
                    yhi = xhi * c + xlo * sn;      // d >= 64: x*cos + x_lo*sin
                } else {
                    ylo = xlo; yhi = xhi;
                }
                out[orow + d]      = ylo;
                out[orow + d + 64] = yhi;
            }
        }
    }
}

// ---------------------------------------------------------------- launch ----
extern "C" void kernel_launch(void* const* d_in, const int* in_sizes, int n_in,
                              void* d_out, int out_size, void* d_ws, size_t ws_size,
                              hipStream_t stream) {
    const float* hs   = (const float*)d_in[0];
    const float* cosp = (const float*)d_in[1];
    const float* sinp = (const float*)d_in[2];
    const float* Wq   = (const float*)d_in[3];
    const float* bq   = (const float*)d_in[4];
    const float* Wk   = (const float*)d_in[5];
    const float* bk   = (const float*)d_in[6];
    const float* Wv   = (const float*)d_in[7];
    const float* bv   = (const float*)d_in[8];
    float* out = (float*)d_out;

    bf16* Abf = (bf16*)d_ws;                      // 8192x3584 bf16 = 58.7 MB
    bf16* Btb = Abf + (size_t)MM * KK;            // 4608x3584 bf16 = 33.0 MB

    int n8 = MM * KK / 8;
    cvt_a<<<(n8 + 255) / 256, 256, 0, stream>>>(hs, Abf, n8);
    tr_cvt<<<dim3(HH / 32, KK / 32), 256, 0, stream>>>(Wq, Btb, HH, 0);
    tr_cvt<<<dim3(512 / 32, KK / 32), 256, 0, stream>>>(Wk, Btb, 512, 3584);
    tr_cvt<<<dim3(512 / 32, KK / 32), 256, 0, stream>>>(Wv, Btb, 512, 4096);
    qkv_gemm<<<NBM * NBN, 256, 0, stream>>>(Abf, Btb, bq, bk, bv, cosp, sinp, out);
}

// Round 2
// 664.999 us; speedup vs baseline: 1.0013x; 1.0013x over previous
//
#include <hip/hip_runtime.h>
#include <hip/hip_bf16.h>
#include <cstdint>
#include <cstddef>

// Problem constants (Qwen2: B=2,S=4096,H=3584,NH=28,NKV=4,D=128)
#define SS 4096
#define HH 3584
#define NHQ 28
#define NKVH 4
#define DD 128
#define MM 8192                 // B*S
#define NN 4608                 // (NH+2*NKV)*D
#define KK 3584
#define NKT 112                 // KK/32
#define NBM 64                  // MM/128
#define NBN 36                  // NN/128
#define QOFF 0
#define KOFF 29360128ULL        // B*NH*S*D
#define VOFF 33554432ULL        // KOFF + B*NKV*S*D

// prep kernel block ranges
#define NB_CVT 7168             // MM*KK/16/256
#define NB_TRQ 12544            // (3584/32)*(3584/32)
#define NB_TRK 1792             // (512/32)*(3584/32)
#define NB_PREP (NB_CVT + NB_TRQ + 2*NB_TRK)

typedef __bf16 bf16;
typedef bf16  bf16x8  __attribute__((ext_vector_type(8)));
typedef float floatx4 __attribute__((ext_vector_type(4)));

// ------------------------------------------------------------- fused prep ---
// blocks [0, NB_CVT):             A fp32 -> bf16 (16 floats / thread)
// blocks [NB_CVT, ...):           W transpose+cvt into Bt (32x32 LDS tiles)
__global__ __launch_bounds__(256) void prep(
    const float* __restrict__ hs, const float* __restrict__ Wq,
    const float* __restrict__ Wk, const float* __restrict__ Wv,
    bf16* __restrict__ Abf, bf16* __restrict__ Bt) {

    int blk = blockIdx.x;
    if (blk < NB_CVT) {
        size_t i = (size_t)blk * 256 + threadIdx.x;      // 16 floats per thread
        const float4* s = (const float4*)hs;
        float4 a = s[4 * i], b = s[4 * i + 1], c = s[4 * i + 2], d = s[4 * i + 3];
        bf16x8 o0, o1;
        o0[0] = (bf16)a.x; o0[1] = (bf16)a.y; o0[2] = (bf16)a.z; o0[3] = (bf16)a.w;
        o0[4] = (bf16)b.x; o0[5] = (bf16)b.y; o0[6] = (bf16)b.z; o0[7] = (bf16)b.w;
        o1[0] = (bf16)c.x; o1[1] = (bf16)c.y; o1[2] = (bf16)c.z; o1[3] = (bf16)c.w;
        o1[4] = (bf16)d.x; o1[5] = (bf16)d.y; o1[6] = (bf16)d.z; o1[7] = (bf16)d.w;
        *(bf16x8*)(Abf + i * 16)     = o0;
        *(bf16x8*)(Abf + i * 16 + 8) = o1;
        return;
    }
    // ---- transpose part ----
    const float* W; int ncols, row_off, nb, kb;
    int t = blk - NB_CVT;
    if (t < NB_TRQ)              { W = Wq; ncols = 3584; row_off = 0;    nb = t % 112; kb = t / 112; }
    else if (t < NB_TRQ + NB_TRK){ int u = t - NB_TRQ;          W = Wk; ncols = 512; row_off = 3584; nb = u % 16; kb = u / 16; }
    else                         { int u = t - NB_TRQ - NB_TRK; W = Wv; ncols = 512; row_off = 4096; nb = u % 16; kb = u / 16; }

    __shared__ float tile[32][33];
    int n0 = nb * 32, k0 = kb * 32;
    int lx = threadIdx.x & 31;
    int ly = threadIdx.x >> 5;          // 0..7
#pragma unroll
    for (int i = 0; i < 32; i += 8)
        tile[ly + i][lx] = W[(size_t)(k0 + ly + i) * ncols + n0 + lx];
    __syncthreads();
#pragma unroll
    for (int i = 0; i < 32; i += 8)
        Bt[(size_t)(row_off + n0 + ly + i) * KK + k0 + lx] = (bf16)tile[lx][ly + i];
}

// ----------------------------------------------------------------- GEMM -----
__device__ __forceinline__ void g2l16(const void* g, void* l) {
    __builtin_amdgcn_global_load_lds(
        (const __attribute__((address_space(1))) void*)g,
        (__attribute__((address_space(3))) void*)l, 16, 0, 0);
}

__global__ __launch_bounds__(256) void qkv_gemm(
    const bf16* __restrict__ A, const bf16* __restrict__ Bt,
    const float* __restrict__ bq, const float* __restrict__ bk,
    const float* __restrict__ bv, const float* __restrict__ cosp,
    const float* __restrict__ sinp, float* __restrict__ out) {

    __shared__ __align__(16) bf16 As[128 * 32];   // (row, k) row-major, 8 KB
    __shared__ __align__(16) bf16 Bs[128 * 32];   // (n,   k) row-major, 8 KB

    const int tid  = threadIdx.x;
    const int lane = tid & 63;
    const int wave = tid >> 6;          // 0..3
    const int wm   = wave >> 1;         // wave m-half
    const int wn   = wave & 1;          // wave n-group
    const int bm   = blockIdx.x / NBN;
    const int bn   = blockIdx.x % NBN;
    const int m0   = bm * 128;
    const int n0   = bn * 128;          // block owns exactly one head (128 cols)

    // ---- staging: tile row = wave*32 + {0,16} + srow, k-chunk = skq (16B units)
    // XOR-swizzle the SOURCE k-chunk by (row&3) so reads are bank-conflict-free.
    // LDS dest stays wave-uniform base + lane*16B (required by global_load_lds).
    const int srow = lane >> 2;
    const int skq  = lane & 3;
    const int skq2 = skq ^ (srow & 3);           // (srow+16)&3 == srow&3, so ok for both halves
    const bf16* ag0 = A  + (size_t)(m0 + wave * 32 + srow) * KK + skq2 * 8;
    const bf16* ag1 = ag0 + (size_t)16 * KK;
    const bf16* bg0 = Bt + (size_t)(n0 + wave * 32 + srow) * KK + skq2 * 8;
    const bf16* bg1 = bg0 + (size_t)16 * KK;
    bf16* al0 = As + (wave * 2 + 0) * 512 + lane * 8;
    bf16* al1 = As + (wave * 2 + 1) * 512 + lane * 8;
    bf16* bl0 = Bs + (wave * 2 + 0) * 512 + lane * 8;
    bf16* bl1 = Bs + (wave * 2 + 1) * 512 + lane * 8;

    // ---- fragment reads (16x16x32: m/n = lane&15, k = (lane>>4)*8+j)
    // chunk stored at c = q ^ (row&3); row bases are multiples of 16 so row&3 == fr&3
    const int fr = lane & 15;
    const int fq = lane >> 4;
    const int fc = (fq ^ (fr & 3)) * 8;
    const bf16* ar[4];
    const bf16* br[4];
#pragma unroll
    for (int mi = 0; mi < 4; ++mi)
        ar[mi] = As + (wm * 64 + mi * 16 + fr) * 32 + fc;
    // RoPE-friendly n-tile assignment: wave wn owns col bases
    //   ni=0: wn*32+0   ni=1: wn*32+64   ni=2: wn*32+16   ni=3: wn*32+80
    // so (2p, 2p+1) is the (d, d+64) rotate pair in the SAME lane.
#pragma unroll
    for (int ni = 0; ni < 4; ++ni) {
        int ncol = wn * 32 + (ni >> 1) * 16 + (ni & 1) * 64;
        br[ni] = Bs + (ncol + fr) * 32 + fc;
    }

    floatx4 acc[4][4];
#pragma unroll
    for (int mi = 0; mi < 4; ++mi)
#pragma unroll
        for (int ni = 0; ni < 4; ++ni)
            acc[mi][ni] = (floatx4){0.f, 0.f, 0.f, 0.f};

    for (int kt = 0; kt < NKT; ++kt) {
        __syncthreads();                      // previous compute done
        g2l16(ag0, al0); g2l16(ag1, al1);
        g2l16(bg0, bl0); g2l16(bg1, bl1);
        ag0 += 32; ag1 += 32; bg0 += 32; bg1 += 32;
        __syncthreads();                      // drains vmcnt -> LDS tiles ready

        bf16x8 af[4], bfr[4];
#pragma unroll
        for (int mi = 0; mi < 4; ++mi) af[mi] = *(const bf16x8*)ar[mi];
#pragma unroll
        for (int ni = 0; ni < 4; ++ni) bfr[ni] = *(const bf16x8*)br[ni];
#pragma unroll
        for (int mi = 0; mi < 4; ++mi)
#pragma unroll
            for (int ni = 0; ni < 4; ++ni)
                acc[mi][ni] = __builtin_amdgcn_mfma_f32_16x16x32_bf16(
                    af[mi], bfr[ni], acc[mi][ni], 0, 0, 0);
    }

    // ---- epilogue: bias + RoPE (register-local pairs) + permuted store -----
    const float* bias;
    int h, nh;
    size_t obase;
    bool rope;
    if (n0 < 3584)      { bias = bq + n0;          h = n0 >> 7;          obase = QOFF; nh = NHQ;  rope = true;  }
    else if (n0 < 4096) { bias = bk + (n0 - 3584); h = (n0 - 3584) >> 7; obase = KOFF; nh = NKVH; rope = true;  }
    else                { bias = bv + (n0 - 4096); h = (n0 - 4096) >> 7; obase = VOFF; nh = NKVH; rope = false; }

    float blo[2], bhi[2];
#pragma unroll
    for (int p = 0; p < 2; ++p) {
        int d = wn * 32 + p * 16 + fr;     // in [0,64)
        blo[p] = bias[d];
        bhi[p] = bias[d + 64];
    }

#pragma unroll
    for (int mi = 0; mi < 4; ++mi) {
#pragma unroll
        for (int r = 0; r < 4; ++r) {
            int m = m0 + wm * 64 + mi * 16 + fq * 4 + r;   // C/D: row=quad*4+reg
            int b = m >> 12;                                // m / S
            int s = m & 4095;                               // m % S
            size_t orow = obase + ((size_t)(b * nh + h) * SS + s) * DD;
#pragma unroll
            for (int p = 0; p < 2; ++p) {
                int d = wn * 32 + p * 16 + fr;
                float xlo = acc[mi][2 * p][r] + blo[p];
                float xhi = acc[mi][2 * p + 1][r] + bhi[p];
                float ylo, yhi;
                if (rope) {
                    float c  = cosp[(size_t)m * DD + d];
                    float sn = sinp[(size_t)m * DD + d];
                    ylo = xlo * c - xhi * sn;      // d < 64:  x*cos - x_hi*sin
                    yhi = xhi * c + xlo * sn;      // d >= 64: x*cos + x_lo*sin
                } else {
                    ylo = xlo; yhi = xhi;
                }
                out[orow + d]      = ylo;
                out[orow + d + 64] = yhi;
            }
        }
    }
}

// ---------------------------------------------------------------- launch ----
extern "C" void kernel_launch(void* const* d_in, const int* in_sizes, int n_in,
                              void* d_out, int out_size, void* d_ws, size_t ws_size,
                              hipStream_t stream) {
    const float* hs   = (const float*)d_in[0];
    const float* cosp = (const float*)d_in[1];
    const float* sinp = (const float*)d_in[2];
    const float* Wq   = (const float*)d_in[3];
    const float* bq   = (const float*)d_in[4];
    const float* Wk   = (const float*)d_in[5];
    const float* bk   = (const float*)d_in[6];
    const float* Wv   = (const float*)d_in[7];
    const float* bv   = (const float*)d_in[8];
    float* out = (float*)d_out;

    bf16* Abf = (bf16*)d_ws;                      // 8192x3584 bf16 = 58.7 MB
    bf16* Btb = Abf + (size_t)MM * KK;            // 4608x3584 bf16 = 33.0 MB

    prep<<<NB_PREP, 256, 0, stream>>>(hs, Wq, Wk, Wv, Abf, Btb);
    qkv_gemm<<<NBM * NBN, 256, 0, stream>>>(Abf, Btb, bq, bk, bv, cosp, sinp, out);
}